// Round 1
// baseline (251.926 us; speedup 1.0000x reference)
//
#include <hip/hip_runtime.h>

// ---- problem constants (from reference) ----
#define N_NODES   100000
#define T_TYPES   4
#define E_EDGES   400000
#define E4        100000                    // int4 groups per type-array
#define G_TOT     400000                    // total int4 groups = TE_TOT/4
#define C_CH      2
#define W_INF     128
#define DD        64
#define NUM_CLASS 16
#define BETA      0.5f
#define M_TGT     10000

// 64-row sub-bucket CSR build
#define NSB       1563                      // ceil(100000/64) sub-buckets
#define NSB_PAD   1568
#define SBPAD     1408                      // slots/sub-bucket (mean 1024, sd 32 -> +12 sigma)
#define CHUNK_G   1024                      // int4 groups per partition block (4096 edges)
#define NPART_BLK 391                       // ceil(400000/1024)
#define PROJ_BLK  1563                      // ceil(100000/64)

// bf16 planes: u32 at [n*64 + d] = bf16(ch0) | bf16(ch1)<<16
static const size_t PLANE2 = (size_t)N_NODES * DD;    // u32 elements per plane

typedef __attribute__((ext_vector_type(8))) short short8x;   // 8 bf16 (4 VGPRs)
typedef __attribute__((ext_vector_type(4))) float f32x4;     // MFMA C/D

__device__ __forceinline__ unsigned bf16rne(float x) {   // RNE f32 -> bf16 bits
    unsigned u = __float_as_uint(x);
    return (u + 0x7FFFu + ((u >> 16) & 1u)) >> 16;
}
__device__ __forceinline__ unsigned packbf(float a, float b) {
    return bf16rne(a) | (bf16rne(b) << 16);
}
__device__ __forceinline__ float bflo(unsigned u) { return __uint_as_float(u << 16); }
__device__ __forceinline__ float bfhi(unsigned u) { return __uint_as_float(u & 0xFFFF0000u); }

__device__ __forceinline__ void load_filter(const float* cw, int layer,
                                            float* f0, float* f1) {
    float m0 = -1e30f, m1 = -1e30f;
    #pragma unroll
    for (int t = 0; t < T_TYPES; ++t) {
        f0[t] = cw[layer * C_CH * T_TYPES + t];
        f1[t] = cw[layer * C_CH * T_TYPES + T_TYPES + t];
        m0 = fmaxf(m0, f0[t]); m1 = fmaxf(m1, f1[t]);
    }
    float s0 = 0.f, s1 = 0.f;
    #pragma unroll
    for (int t = 0; t < T_TYPES; ++t) {
        f0[t] = __expf(f0[t] - m0); s0 += f0[t];
        f1[t] = __expf(f1[t] - m1); s1 += f1[t];
    }
    #pragma unroll
    for (int t = 0; t < T_TYPES; ++t) { f0[t] /= s0; f1[t] /= s1; }
}

// ---------------------------------------------------------------------------
// prep: Wsb[c][d][k] = bf16(Ws[c][k][d]) (blocks 0..63) + cursor init (64..70)
// ---------------------------------------------------------------------------
__global__ void prep_kernel(const float* __restrict__ Ws,
                            unsigned short* __restrict__ Wsb,
                            int* __restrict__ cursor) {
    int b = blockIdx.x;
    int tid = threadIdx.x;
    if (b < 64) {
        int idx = b * 256 + tid;
        int c   = idx >> 13;
        int rem = idx & 8191;
        int d   = rem >> 7;
        int k   = rem & 127;
        Wsb[idx] = (unsigned short)bf16rne(Ws[c * (W_INF * DD) + k * DD + d]);
    } else {
        int idx = (b - 64) * 256 + tid;
        if (idx < NSB) cursor[idx] = idx * SBPAD;
    }
}

// ---------------------------------------------------------------------------
// Fused: blocks [0, NPART_BLK) partition edges into 64-row sub-buckets with
// DIRECT scatter stores (no LDS edge staging -> 12.5 KB LDS, 8 blocks/CU).
// Blocks [NPART_BLK, +PROJ_BLK) run the MFMA projection LDS-free: per-lane
// A-fragments loaded straight from X (wave consumes every fetched line).
// partition record: edata2[pos] = { col | t<<17 | (row&63)<<19 ,
//                                   packbf(val*f0_l1[t], val*f1_l1[t]) }
// ---------------------------------------------------------------------------
__global__ __launch_bounds__(256) void build_proj_kernel(
        const int* __restrict__ edge_index,
        const float* __restrict__ edge_value,
        const float* __restrict__ cw,
        int* __restrict__ cursor,
        int2* __restrict__ edata2,
        const float* __restrict__ X,
        const unsigned short* __restrict__ Wsb,
        unsigned* __restrict__ Xp16) {
    __shared__ int cnt[NSB_PAD];
    __shared__ int gbase[NSB_PAD];
    int tid = threadIdx.x;

    if (blockIdx.x < NPART_BLK) {
        // ---------------- partition ----------------
        int p = blockIdx.x;
        for (int j = tid; j < NSB; j += 256) cnt[j] = 0;
        __syncthreads();

        float f0[T_TYPES], f1[T_TYPES];
        load_filter(cw, 0, f0, f1);

        int px[16], rk[16], bk[16];
        bool gv[4];
        #pragma unroll
        for (int g = 0; g < 4; ++g) {
            int idx = p * CHUNK_G + g * 256 + tid;
            gv[g] = idx < G_TOT;
            if (gv[g]) {
                int t = idx / E4, r = idx - t * E4;
                const int* bptr = edge_index + (size_t)t * 2 * E_EDGES;
                int4 rw = ((const int4*)bptr)[r];
                int4 cl = ((const int4*)(bptr + E_EDGES))[r];
                int tb = t << 17;
                int rr[4] = {rw.x, rw.y, rw.z, rw.w};
                int cc[4] = {cl.x, cl.y, cl.z, cl.w};
                #pragma unroll
                for (int k = 0; k < 4; ++k) {
                    int kk = g * 4 + k;
                    int b = rr[k] >> 6;
                    px[kk] = cc[k] | tb | ((rr[k] & 63) << 19);
                    bk[kk] = b;
                    rk[kk] = atomicAdd(&cnt[b], 1);
                }
            }
        }
        __syncthreads();
        for (int j = tid; j < NSB; j += 256)
            gbase[j] = cnt[j] ? atomicAdd(&cursor[j], cnt[j]) : 0;
        __syncthreads();
        #pragma unroll
        for (int g = 0; g < 4; ++g) {
            if (gv[g]) {
                int idx = p * CHUNK_G + g * 256 + tid;
                int t = idx / E4, r = idx - t * E4;
                float4 vv = ((const float4*)(edge_value + (size_t)t * E_EDGES))[r];
                float vf[4] = {vv.x, vv.y, vv.z, vv.w};
                #pragma unroll
                for (int k = 0; k < 4; ++k) {
                    int kk = g * 4 + k;
                    int tt = (px[kk] >> 17) & 3;
                    edata2[(size_t)gbase[bk[kk]] + rk[kk]] =
                        make_int2(px[kk], (int)packbf(vf[k] * f0[tt], vf[k] * f1[tt]));
                }
            }
        }
    } else {
        // ---------------- MFMA projection (LDS-free) ----------------
        int row0 = (blockIdx.x - NPART_BLK) * 64;
        int wave = tid >> 6, lane = tid & 63;
        int m = lane & 15, q = lane >> 4;
        int arow = row0 + wave * 16 + m;
        const float4* X4 = (const float4*)X;
        union { short8x s; uint4 u; } A[4];
        bool valid = arow < N_NODES;
        #pragma unroll
        for (int ks = 0; ks < 4; ++ks) {
            float4 va = make_float4(0.f, 0.f, 0.f, 0.f), vb = va;
            if (valid) {
                va = X4[(size_t)arow * 32 + ks * 8 + q * 2];
                vb = X4[(size_t)arow * 32 + ks * 8 + q * 2 + 1];
            }
            A[ks].u = make_uint4(packbf(va.x, va.y), packbf(va.z, va.w),
                                 packbf(vb.x, vb.y), packbf(vb.z, vb.w));
        }

        #pragma unroll
        for (int ct = 0; ct < 4; ++ct) {
            f32x4 acc0 = {0.f, 0.f, 0.f, 0.f};
            f32x4 acc1 = {0.f, 0.f, 0.f, 0.f};
            #pragma unroll
            for (int ks = 0; ks < 4; ++ks) {
                short8x B0 = *(const short8x*)(Wsb + (ct * 16 + m) * 128 + ks * 32 + q * 8);
                short8x B1 = *(const short8x*)(Wsb + 8192 + (ct * 16 + m) * 128 + ks * 32 + q * 8);
                acc0 = __builtin_amdgcn_mfma_f32_16x16x32_bf16(A[ks].s, B0, acc0, 0, 0, 0);
                acc1 = __builtin_amdgcn_mfma_f32_16x16x32_bf16(A[ks].s, B1, acc1, 0, 0, 0);
            }
            #pragma unroll
            for (int r = 0; r < 4; ++r) {
                int row = row0 + wave * 16 + q * 4 + r;
                if (row < N_NODES)
                    Xp16[(size_t)row * DD + ct * 16 + m] = packbf(acc0[r], acc1[r]);
            }
        }
    }
}

// ---------------------------------------------------------------------------
// Quarter-wave bf16 gather helpers: s16 = lane&15 covers d = {4s..4s+3} both
// channels as uint4 = 16 B/lane; sub = lane>>4 interleaves 4 edges per wave.
// ---------------------------------------------------------------------------
__device__ __forceinline__ void qfma(const uint4 h, unsigned wp,
                                     float4& a, float4& b) {
    float w0 = bflo(wp), w1 = bfhi(wp);
    a.x = fmaf(w0, bflo(h.x), a.x);
    a.y = fmaf(w1, bfhi(h.x), a.y);
    a.z = fmaf(w0, bflo(h.y), a.z);
    a.w = fmaf(w1, bfhi(h.y), a.w);
    b.x = fmaf(w0, bflo(h.z), b.x);
    b.y = fmaf(w1, bfhi(h.z), b.y);
    b.z = fmaf(w0, bflo(h.w), b.z);
    b.w = fmaf(w1, bfhi(h.w), b.w);
}

__device__ __forceinline__ void qreduce(float4& a, float4& b) {
    a.x += __shfl_xor(a.x, 16); a.y += __shfl_xor(a.y, 16);
    a.z += __shfl_xor(a.z, 16); a.w += __shfl_xor(a.w, 16);
    b.x += __shfl_xor(b.x, 16); b.y += __shfl_xor(b.y, 16);
    b.z += __shfl_xor(b.z, 16); b.w += __shfl_xor(b.w, 16);
    a.x += __shfl_xor(a.x, 32); a.y += __shfl_xor(a.y, 32);
    a.z += __shfl_xor(a.z, 32); a.w += __shfl_xor(a.w, 32);
    b.x += __shfl_xor(b.x, 32); b.y += __shfl_xor(b.y, 32);
    b.z += __shfl_xor(b.z, 32); b.w += __shfl_xor(b.w, 32);
}

__device__ __forceinline__ int row_beg(const int* offs, int row) {
    return ((row & 63) == 0) ? (row >> 6) * SBPAD : offs[row - 1];
}

// ---------------------------------------------------------------------------
// Fused per-sub-bucket (64 rows) row-sort + layer-1 gather.
//  - two L2-hot passes over the sub-bucket edges: count rows, then scatter
//    into LDS sorted order
//  - stream sorted list back IN PLACE (consumed only by tgt_tail) + offs
//  - layer-1 gather straight out of the LDS-resident sorted list
// 12 KB LDS, 256 threads -> 8 blocks/CU.
// ---------------------------------------------------------------------------
__global__ __launch_bounds__(256) void sortgather_kernel(
        const int* __restrict__ cursor,
        int2* __restrict__ edata2,
        int* __restrict__ offs,
        const unsigned* __restrict__ Hin16,
        unsigned* __restrict__ Hout16) {
    __shared__ int rcnt[64];
    __shared__ int rbase[64];
    __shared__ int rcur[64];
    __shared__ int2 ls[SBPAD];
    int tid = threadIdx.x;
    int sb = blockIdx.x;
    int base = sb * SBPAD;
    int cntb = cursor[sb] - base;

    if (tid < 64) rcnt[tid] = 0;
    __syncthreads();
    for (int j = tid; j < cntb; j += 256)
        atomicAdd(&rcnt[(edata2[base + j].x >> 19) & 63], 1);
    __syncthreads();
    if (tid < 64) {                                // scan 64 row counts (wave 0)
        int c = rcnt[tid];
        int inc = c;
        #pragma unroll
        for (int off = 1; off < 64; off <<= 1) {
            int v = __shfl_up(inc, off);
            if (tid >= off) inc += v;
        }
        rbase[tid] = inc - c;
        rcur[tid]  = inc - c;
    }
    __syncthreads();
    for (int j = tid; j < cntb; j += 256) {
        int2 e = edata2[base + j];
        int pos = atomicAdd(&rcur[(e.x >> 19) & 63], 1);
        ls[pos] = e;
    }
    __syncthreads();

    // stream sorted list back in place (for tgt_tail) + per-row end offsets
    for (int j = tid; j < cntb; j += 256) edata2[base + j] = ls[j];
    int row0 = sb << 6;
    if (tid < 64) {
        int row = row0 + tid;
        if (row < N_NODES) offs[row] = base + rbase[tid] + rcnt[tid];
    }

    // ---------------- layer-1 gather ----------------
    int wv = tid >> 6, lane = tid & 63;
    int s16 = lane & 15, sub = lane >> 4;
    const uint4* hp = (const uint4*)Hin16;
    #pragma unroll 1
    for (int t16 = 0; t16 < 16; ++t16) {
        int lr = wv * 16 + t16;
        int beg = rbase[lr];
        int end = beg + rcnt[lr];
        float4 a = make_float4(0.f, 0.f, 0.f, 0.f);
        float4 b = make_float4(0.f, 0.f, 0.f, 0.f);
        int i = beg + sub;
        for (; i + 4 < end; i += 8) {             // 2 edges per quarter per iter
            int2 e0 = ls[i];
            int2 e1 = ls[i + 4];
            uint4 h0 = hp[(size_t)(e0.x & 0x1FFFF) * 16 + s16];
            uint4 h1 = hp[(size_t)(e1.x & 0x1FFFF) * 16 + s16];
            qfma(h0, (unsigned)e0.y, a, b);
            qfma(h1, (unsigned)e1.y, a, b);
        }
        if (i < end) {
            int2 e = ls[i];
            uint4 h = hp[(size_t)(e.x & 0x1FFFF) * 16 + s16];
            qfma(h, (unsigned)e.y, a, b);
        }
        qreduce(a, b);
        int row = row0 + lr;
        if (sub == 0 && row < N_NODES)
            ((uint4*)Hout16)[(size_t)row * 16 + s16] =
                make_uint4(packbf(a.x, a.y), packbf(a.z, a.w),
                           packbf(b.x, b.y), packbf(b.z, b.w));
    }
}

// ---------------------------------------------------------------------------
// Fused layer-2 gather (target rows) + tail MLP. Block = 4 waves = 4 targets.
// Layer-2 edge weights = stored_l1_weight * (f_l2[t]/f_l1[t]).
// ---------------------------------------------------------------------------
__global__ __launch_bounds__(256) void tgt_tail_kernel(const unsigned* __restrict__ Hin16,
                                                       const unsigned* __restrict__ Xp16,
                                                       const int* __restrict__ offs,
                                                       const int2* __restrict__ edata2,
                                                       const float* __restrict__ cw,
                                                       const int* __restrict__ tgt,
                                                       const float* __restrict__ lin1_w,
                                                       const float* __restrict__ lin1_b,
                                                       const float* __restrict__ lin_w,
                                                       const float* __restrict__ lin_b,
                                                       float* __restrict__ out) {
    __shared__ float l1w[W_INF * DD];        // 32 KB
    __shared__ float lw[DD * NUM_CLASS];     // 4 KB
    __shared__ float l1b[DD];
    __shared__ float lb[NUM_CLASS];
    __shared__ float hc[4][W_INF];
    __shared__ float hmid[4][DD];

    int tid = threadIdx.x;
    {
        const float4* g = (const float4*)lin1_w;
        float4* s = (float4*)l1w;
        #pragma unroll
        for (int i = 0; i < 8; ++i) s[tid + 256 * i] = g[tid + 256 * i];
        ((float4*)lw)[tid] = ((const float4*)lin_w)[tid];
        if (tid < DD) l1b[tid] = lin1_b[tid];
        else if (tid < DD + NUM_CLASS) lb[tid - DD] = lin_b[tid - DD];
    }

    float f0a[T_TYPES], f1a[T_TYPES], f0b[T_TYPES], f1b[T_TYPES];
    load_filter(cw, 0, f0a, f1a);
    load_filter(cw, 1, f0b, f1b);
    float r0[T_TYPES], r1[T_TYPES];
    #pragma unroll
    for (int t = 0; t < T_TYPES; ++t) { r0[t] = f0b[t] / f0a[t]; r1[t] = f1b[t] / f1a[t]; }

    int w = tid >> 6, lane = tid & 63;
    int s16 = lane & 15, sub = lane >> 4;
    int m = blockIdx.x * 4 + w;               // M = 10000 = 2500*4
    int row = tgt[m];
    int beg = row_beg(offs, row);
    int end = offs[row];
    const uint4* hp = (const uint4*)Hin16;
    float4 a = make_float4(0.f, 0.f, 0.f, 0.f);
    float4 b = make_float4(0.f, 0.f, 0.f, 0.f);
    for (int i = beg + sub; i < end; i += 4) {
        int2 e = edata2[i];
        int t = (e.x >> 17) & 3;
        uint4 h = hp[(size_t)(e.x & 0x1FFFF) * 16 + s16];
        unsigned wp = (unsigned)e.y;
        float w0 = bflo(wp) * r0[t], w1 = bfhi(wp) * r1[t];
        a.x = fmaf(w0, bflo(h.x), a.x);
        a.y = fmaf(w1, bfhi(h.x), a.y);
        a.z = fmaf(w0, bflo(h.y), a.z);
        a.w = fmaf(w1, bfhi(h.y), a.w);
        b.x = fmaf(w0, bflo(h.z), b.x);
        b.y = fmaf(w1, bfhi(h.z), b.y);
        b.z = fmaf(w0, bflo(h.w), b.z);
        b.w = fmaf(w1, bfhi(h.w), b.w);
    }
    qreduce(a, b);

    if (sub == 0) {
        uint4 xu = ((const uint4*)Xp16)[(size_t)row * 16 + s16];
        int d0 = 4 * s16;
        hc[w][d0 + 0]      = fmaxf(BETA * bflo(xu.x) + (1.f - BETA) * a.x, 0.f);
        hc[w][DD + d0 + 0] = fmaxf(BETA * bfhi(xu.x) + (1.f - BETA) * a.y, 0.f);
        hc[w][d0 + 1]      = fmaxf(BETA * bflo(xu.y) + (1.f - BETA) * a.z, 0.f);
        hc[w][DD + d0 + 1] = fmaxf(BETA * bfhi(xu.y) + (1.f - BETA) * a.w, 0.f);
        hc[w][d0 + 2]      = fmaxf(BETA * bflo(xu.z) + (1.f - BETA) * b.x, 0.f);
        hc[w][DD + d0 + 2] = fmaxf(BETA * bfhi(xu.z) + (1.f - BETA) * b.y, 0.f);
        hc[w][d0 + 3]      = fmaxf(BETA * bflo(xu.w) + (1.f - BETA) * b.z, 0.f);
        hc[w][DD + d0 + 3] = fmaxf(BETA * bfhi(xu.w) + (1.f - BETA) * b.w, 0.f);
    }
    __syncthreads();

    float a1 = l1b[lane];
    #pragma unroll 8
    for (int k = 0; k < W_INF; ++k)
        a1 = fmaf(hc[w][k], l1w[k * DD + lane], a1);
    hmid[w][lane] = a1;
    __syncthreads();

    if (lane < NUM_CLASS) {
        float o = lb[lane];
        #pragma unroll 8
        for (int k = 0; k < DD; ++k)
            o = fmaf(hmid[w][k], lw[k * NUM_CLASS + lane], o);
        out[(size_t)m * NUM_CLASS + lane] = o;
    }
}

// ---------------------------------------------------------------------------
extern "C" void kernel_launch(void* const* d_in, const int* in_sizes, int n_in,
                              void* d_out, int out_size, void* d_ws, size_t ws_size,
                              hipStream_t stream) {
    const float* X            = (const float*)d_in[0];
    const float* edge_value   = (const float*)d_in[1];
    const float* conv_weights = (const float*)d_in[2];
    const float* Ws           = (const float*)d_in[3];
    const float* lin1_w       = (const float*)d_in[4];
    const float* lin1_b       = (const float*)d_in[5];
    const float* lin_w        = (const float*)d_in[6];
    const float* lin_b        = (const float*)d_in[7];
    const int*   edge_index   = (const int*)d_in[8];
    const int*   target_x     = (const int*)d_in[9];
    float* out = (float*)d_out;

    unsigned*       Xp16 = (unsigned*)d_ws;                   // 25.6 MB
    unsigned*       H116 = Xp16 + PLANE2;                     // 25.6 MB
    unsigned short* Wsb  = (unsigned short*)(H116 + PLANE2);  // 32 KB
    int*            offs = (int*)(Wsb + C_CH * W_INF * DD);   // N ints
    int*            cursor = offs + N_NODES;                  // 1600
    int2*           edata2 = (int2*)(cursor + 1600);          // NSB*SBPAD int2 (17.6 MB)

    prep_kernel<<<71, 256, 0, stream>>>(Ws, Wsb, cursor);
    build_proj_kernel<<<NPART_BLK + PROJ_BLK, 256, 0, stream>>>(
        edge_index, edge_value, conv_weights, cursor, edata2, X, Wsb, Xp16);
    sortgather_kernel<<<NSB, 256, 0, stream>>>(cursor, edata2, offs, Xp16, H116);
    tgt_tail_kernel<<<M_TGT / 4, 256, 0, stream>>>(H116, Xp16, offs, edata2,
                                                   conv_weights, target_x,
                                                   lin1_w, lin1_b, lin_w, lin_b, out);
}